// Round 12
// baseline (903.714 us; speedup 1.0000x reference)
//
#include <hip/hip_runtime.h>

// GAT layer: N=100000 nodes, E=1.6M edges, IN=128, H=4, F=16 (H*F=64)
// fp32 in/out. 4 dispatches:
//   memset:    bucketCount+bucketCursor = 0
//   gemm_att (+fused bcount tail blocks):
//              h=x@W via bf16 MFMA; att = x@(W@a) folded into 8 extra
//              B-columns. h stored bf16.
//   bscatter:  LDS-staged radix partition into 782 buckets of 128 dst nodes,
//              packed (src<<7|dstloc) ints; block 0 publishes bucketBase.
//   agg_accum: one block per bucket. LDS acc[128][65] (pad-65 -> bank =
//              (dloc+f)&31, conflict-free) + l[128][5] + cached att_d.
//              Each thread owns whole edges: att_s float4 gather, 4 exps
//              (no max-shift: |e|<~25 fp32-safe; softmax shift-invariant),
//              hmat row gather, 64 LDS float atomic accumulates. Epilogue
//              ELU(acc/l) with coalesced float4 stores. No CSR needed.

#define NEG_SLOPE 0.2f
#define BSHIFT 7            // 128 nodes per bucket
#define BNODES 128
#define NBPAD 1024
#define CH 4096             // edges per bscatter block (32 KB LDS staging)
#define BCB 512             // bcount blocks fused into gemm grid

typedef __bf16 bf16x8 __attribute__((ext_vector_type(8)));
typedef float  f32x4  __attribute__((ext_vector_type(4)));

static __device__ __forceinline__ unsigned f2b(float f) {
    union { float f; unsigned u; } v; v.f = f;
    return (v.u + 0x7fffu + ((v.u >> 16) & 1u)) >> 16;   // RNE
}
static __device__ __forceinline__ float u2f(unsigned u) {
    union { unsigned u32; float f; } v; v.u32 = u; return v.f;
}

// ---------------- K1: h = x@W (bf16 MFMA) + att MFMA + fused bcount -------
__global__ __launch_bounds__(256) void gemm_att_kernel(
    const float* __restrict__ x,       // [N,128]
    const float* __restrict__ W,       // [128,64]
    const float* __restrict__ a_src,   // [4,16]
    const float* __restrict__ a_dst,   // [4,16]
    unsigned short* __restrict__ h_out,// bf16 [N,64]
    float* __restrict__ att_s_o,       // [N,4]
    float* __restrict__ att_d_o,       // [N,4]
    const int* __restrict__ dst,       // [E] (bcount part)
    int* __restrict__ bucketCount,
    int N, int E, int gemmBlocks)
{
    __shared__ bf16x8 Wswz[20][64];    // 20 KB
    __shared__ int c[NBPAD];           // 4 KB (bcount path)
    int t = threadIdx.x;

    if (blockIdx.x >= gemmBlocks) {    // ---- bcount path ----
        int bid = blockIdx.x - gemmBlocks;
        for (int j = t; j < NBPAD; j += 256) c[j] = 0;
        __syncthreads();
        for (int e = bid * 256 + t; e < E; e += BCB * 256)
            atomicAdd(&c[dst[e] >> BSHIFT], 1);
        __syncthreads();
        for (int j = t; j < NBPAD; j += 256)
            if (c[j]) atomicAdd(&bucketCount[j], c[j]);
        return;
    }

    // ---- W swizzle ----
    for (int i = t; i < 8192; i += 256) {            // W[k][n], coalesced
        int k = i >> 6, n = i & 63;
        __bf16* dp = (__bf16*)&Wswz[((n >> 4) << 2) | (k >> 5)]
                                   [(((k >> 3) & 3) << 4) | (n & 15)];
        dp[k & 7] = (__bf16)W[i];
    }
    // ---- ws/wd fold: entry 16+tt, cols 0..7 = [ws|wd], cols 8..15 = 0 ----
    for (int i = t; i < 1024; i += 256) {            // k(128) x c7(8)
        int k = i >> 3, c7 = i & 7;
        int hd = c7 & 3;
        const float* aa = (c7 < 4) ? a_src : a_dst;
        float sum = 0.f;
        #pragma unroll
        for (int f = 0; f < 16; ++f)
            sum = fmaf(W[k * 64 + hd * 16 + f], aa[hd * 16 + f], sum);
        __bf16* dp = (__bf16*)&Wswz[16 + (k >> 5)][(((k >> 3) & 3) << 4) | c7];
        dp[k & 7] = (__bf16)sum;
        __bf16* dz = (__bf16*)&Wswz[16 + (k >> 5)][(((k >> 3) & 3) << 4) | (8 + c7)];
        dz[k & 7] = (__bf16)0.f;
    }
    __syncthreads();

    int wave = t >> 6;
    int lane = t & 63;
    int col = lane & 15, quad = lane >> 4;
    int node_base = (blockIdx.x * 4 + wave) * 16;
    int arow = min(node_base + col, N - 1);
    const float* xp = x + arow * 128;

    bf16x8 af[4];
    #pragma unroll
    for (int tt = 0; tt < 4; ++tt) {
        float4 xa = *(const float4*)(xp + tt * 32 + quad * 8);
        float4 xb = *(const float4*)(xp + tt * 32 + quad * 8 + 4);
        bf16x8 f;
        f[0] = (__bf16)xa.x; f[1] = (__bf16)xa.y;
        f[2] = (__bf16)xa.z; f[3] = (__bf16)xa.w;
        f[4] = (__bf16)xb.x; f[5] = (__bf16)xb.y;
        f[6] = (__bf16)xb.z; f[7] = (__bf16)xb.w;
        af[tt] = f;
    }

    f32x4 acc[4], accA;
    #pragma unroll
    for (int cb = 0; cb < 4; ++cb) {
        acc[cb] = (f32x4){0.f, 0.f, 0.f, 0.f};
        #pragma unroll
        for (int tt = 0; tt < 4; ++tt)
            acc[cb] = __builtin_amdgcn_mfma_f32_16x16x32_bf16(
                af[tt], Wswz[(cb << 2) | tt][lane], acc[cb], 0, 0, 0);
    }
    accA = (f32x4){0.f, 0.f, 0.f, 0.f};
    #pragma unroll
    for (int tt = 0; tt < 4; ++tt)
        accA = __builtin_amdgcn_mfma_f32_16x16x32_bf16(
            af[tt], Wswz[16 + tt][lane], accA, 0, 0, 0);

    #pragma unroll
    for (int cb = 0; cb < 4; ++cb) {
        #pragma unroll
        for (int r = 0; r < 4; ++r) {
            int node = node_base + quad * 4 + r;
            if (node < N)
                h_out[node * 64 + cb * 16 + col] = (unsigned short)f2b(acc[cb][r]);
        }
    }
    if (col < 8) {
        #pragma unroll
        for (int r = 0; r < 4; ++r) {
            int node = node_base + quad * 4 + r;
            if (node < N) {
                if (col < 4) att_s_o[(node << 2) | col] = accA[r];
                else         att_d_o[(node << 2) | (col - 4)] = accA[r];
            }
        }
    }
}

// ---------------- K2: LDS-staged radix partition -> packed ints -----------
// 782 buckets of 128 nodes; 4 buckets per thread in the scans.
__global__ __launch_bounds__(256) void bscatter_kernel(
    const int* __restrict__ src, const int* __restrict__ dst,
    const int* __restrict__ bucketCount,
    int* __restrict__ bucketCursor, int* __restrict__ bucketBase,
    int* __restrict__ pairs, int nb, int E)
{
    __shared__ int cnt[NBPAD], lo[NBPAD], gpos[NBPAD], cur[NBPAD];
    __shared__ int tsum[256];
    __shared__ int2 staged[CH];        // 32 KB: .x = packed, .y = bucket
    int t = threadIdx.x;
    int base = blockIdx.x * CH;
    int nloc = min(CH, E - base);

    for (int j = t; j < NBPAD; j += 256) cnt[j] = 0;
    __syncthreads();
    for (int i = t; i < nloc; i += 256)
        atomicAdd(&cnt[dst[base + i] >> BSHIFT], 1);
    __syncthreads();

    // local exclusive scan of cnt (4/thread)
    int c0 = cnt[4*t], c1 = cnt[4*t+1], c2 = cnt[4*t+2], c3 = cnt[4*t+3];
    int cs = c0 + c1 + c2 + c3;
    tsum[t] = cs;
    __syncthreads();
    #pragma unroll
    for (int off = 1; off < 256; off <<= 1) {
        int u = (t >= off) ? tsum[t - off] : 0;
        __syncthreads();
        tsum[t] += u;
        __syncthreads();
    }
    int tex = tsum[t] - cs;
    lo[4*t]   = tex;            cur[4*t]   = tex;
    lo[4*t+1] = tex + c0;       cur[4*t+1] = tex + c0;
    lo[4*t+2] = tex + c0 + c1;  cur[4*t+2] = tex + c0 + c1;
    lo[4*t+3] = tex + c0 + c1 + c2; cur[4*t+3] = tex + c0 + c1 + c2;
    __syncthreads();

    // global exclusive scan of bucketCount (4/thread)
    int g0 = (4*t   < nb) ? bucketCount[4*t]   : 0;
    int g1 = (4*t+1 < nb) ? bucketCount[4*t+1] : 0;
    int g2 = (4*t+2 < nb) ? bucketCount[4*t+2] : 0;
    int g3 = (4*t+3 < nb) ? bucketCount[4*t+3] : 0;
    int gs = g0 + g1 + g2 + g3;
    tsum[t] = gs;
    __syncthreads();
    #pragma unroll
    for (int off = 1; off < 256; off <<= 1) {
        int u = (t >= off) ? tsum[t - off] : 0;
        __syncthreads();
        tsum[t] += u;
        __syncthreads();
    }
    int gex = tsum[t] - gs;
    int gexk[4] = {gex, gex + g0, gex + g0 + g1, gex + g0 + g1 + g2};
    int ck[4] = {c0, c1, c2, c3};
    #pragma unroll
    for (int k = 0; k < 4; ++k) {
        int b = 4*t + k;
        gpos[b] = (ck[k] > 0) ? gexk[k] + atomicAdd(&bucketCursor[b], ck[k]) : 0;
        if (blockIdx.x == 0 && b <= nb)
            bucketBase[b] = (b == nb) ? E : gexk[k];
    }
    __syncthreads();

    for (int i = t; i < nloc; i += 256) {
        int d = dst[base + i];
        int s = src[base + i];
        int b = d >> BSHIFT;
        int k = atomicAdd(&cur[b], 1);
        staged[k] = make_int2((s << BSHIFT) | (d & (BNODES - 1)), b);
    }
    __syncthreads();

    for (int i = t; i < nloc; i += 256) {
        int2 p = staged[i];
        pairs[gpos[p.y] + (i - lo[p.y])] = p.x;
    }
}

// ---------------- K3: per-bucket LDS accumulate + ELU ---------------------
// One 256-thread block per bucket of 128 dst nodes.
__global__ __launch_bounds__(256) void agg_accum_kernel(
    const int* __restrict__ pairs,           // [E] packed (s<<7|dloc)
    const int* __restrict__ bucketBase,      // [nb+1]
    const float* __restrict__ att_s,         // [N,4]
    const float* __restrict__ att_d,         // [N,4]
    const unsigned short* __restrict__ hmat, // bf16 [N,64]
    float* __restrict__ out,                 // [N,64]
    int N)
{
    __shared__ float acc_l[BNODES * 65];     // 33.3 KB, bank=(dloc+f)&31
    __shared__ float l_l[BNODES * 5];        // 2.5 KB
    __shared__ float4 attd_l[BNODES];        // 2 KB
    int b = blockIdx.x, t = threadIdx.x;
    int node_lo = b << BSHIFT;

    for (int j = t; j < BNODES * 65; j += 256) acc_l[j] = 0.f;
    for (int j = t; j < BNODES * 5; j += 256) l_l[j] = 0.f;
    if (t < BNODES) {
        int nd = node_lo + t;
        attd_l[t] = (nd < N) ? *(const float4*)(att_d + (nd << 2))
                             : make_float4(0.f, 0.f, 0.f, 0.f);
    }
    int ebase = bucketBase[b];
    int ecnt = bucketBase[b + 1] - ebase;
    __syncthreads();

    for (int i = t; i < ecnt; i += 256) {
        int p = pairs[ebase + i];
        int s = p >> BSHIFT, dloc = p & (BNODES - 1);
        float4 as = *(const float4*)(att_s + (s << 2));
        float4 ad = attd_l[dloc];
        float e0 = as.x + ad.x; e0 = fmaxf(e0, NEG_SLOPE * e0);
        float e1 = as.y + ad.y; e1 = fmaxf(e1, NEG_SLOPE * e1);
        float e2 = as.z + ad.z; e2 = fmaxf(e2, NEG_SLOPE * e2);
        float e3 = as.w + ad.w; e3 = fmaxf(e3, NEG_SLOPE * e3);
        float w[4] = {__expf(e0), __expf(e1), __expf(e2), __expf(e3)};
        float* lrow = l_l + dloc * 5;
        atomicAdd(&lrow[0], w[0]);
        atomicAdd(&lrow[1], w[1]);
        atomicAdd(&lrow[2], w[2]);
        atomicAdd(&lrow[3], w[3]);

        const uint4* hp = (const uint4*)(hmat + (s << 6));
        float* arow = acc_l + dloc * 65;
        #pragma unroll
        for (int u8 = 0; u8 < 8; ++u8) {
            uint4 hv = hp[u8];
            float ww = w[u8 >> 1];
            int fb = u8 << 3;
            atomicAdd(&arow[fb + 0], ww * u2f(hv.x << 16));
            atomicAdd(&arow[fb + 1], ww * u2f(hv.x & 0xffff0000u));
            atomicAdd(&arow[fb + 2], ww * u2f(hv.y << 16));
            atomicAdd(&arow[fb + 3], ww * u2f(hv.y & 0xffff0000u));
            atomicAdd(&arow[fb + 4], ww * u2f(hv.z << 16));
            atomicAdd(&arow[fb + 5], ww * u2f(hv.z & 0xffff0000u));
            atomicAdd(&arow[fb + 6], ww * u2f(hv.w << 16));
            atomicAdd(&arow[fb + 7], ww * u2f(hv.w & 0xffff0000u));
        }
    }
    __syncthreads();

    int nmax = min(BNODES, N - node_lo);
    for (int v = t; v < nmax * 16; v += 256) {   // 16 float4 per node
        int nd = v >> 4, f4 = (v & 15) << 2;
        float linv = 1.0f / (l_l[nd * 5 + (f4 >> 4)] + 1e-16f);
        const float* ar = acc_l + nd * 65 + f4;
        float4 o;
        o.x = ar[0] * linv; o.x = (o.x > 0.f) ? o.x : (__expf(o.x) - 1.f);
        o.y = ar[1] * linv; o.y = (o.y > 0.f) ? o.y : (__expf(o.y) - 1.f);
        o.z = ar[2] * linv; o.z = (o.z > 0.f) ? o.z : (__expf(o.z) - 1.f);
        o.w = ar[3] * linv; o.w = (o.w > 0.f) ? o.w : (__expf(o.w) - 1.f);
        *(float4*)(out + ((node_lo + nd) << 6) + f4) = o;
    }
}

extern "C" void kernel_launch(void* const* d_in, const int* in_sizes, int n_in,
                              void* d_out, int out_size, void* d_ws, size_t ws_size,
                              hipStream_t stream) {
    const float* x     = (const float*)d_in[0];
    const int*   ei    = (const int*)d_in[1];
    const float* W     = (const float*)d_in[2];
    const float* a_src = (const float*)d_in[3];
    const float* a_dst = (const float*)d_in[4];

    int N = in_sizes[0] / 128;
    int E = in_sizes[1] / 2;
    const int* src = ei;
    const int* dst = ei + E;
    int nb = (N + BNODES - 1) / BNODES;       // 782 buckets

    char* ws = (char*)d_ws;
    size_t off = 0;
    unsigned short* hmat = (unsigned short*)(ws + off); off += (size_t)N * 64 * 2; // 12.8 MB
    float* att_s = (float*)(ws + off);  off += (size_t)N * 4 * 4;
    float* att_d = (float*)(ws + off);  off += (size_t)N * 4 * 4;
    int* pairs    = (int*)(ws + off);   off += (size_t)E * 4;        // 6.4 MB
    int* bucketBase   = (int*)(ws + off); off += (NBPAD + 4) * 4;
    int* bucketCount  = (int*)(ws + off); off += NBPAD * 4;          // zeroed
    int* bucketCursor = (int*)(ws + off); off += NBPAD * 4;          // zeroed

    hipMemsetAsync(bucketCount, 0, 2 * NBPAD * 4, stream);

    int gemmBlocks = (N + 63) / 64;           // 1563
    gemm_att_kernel<<<gemmBlocks + BCB, 256, 0, stream>>>(
        x, W, a_src, a_dst, hmat, att_s, att_d, dst, bucketCount,
        N, E, gemmBlocks);

    int blocksS = (E + CH - 1) / CH;          // 391
    bscatter_kernel<<<blocksS, 256, 0, stream>>>(src, dst, bucketCount,
                                                 bucketCursor, bucketBase,
                                                 pairs, nb, E);

    agg_accum_kernel<<<nb, 256, 0, stream>>>(pairs, bucketBase, att_s, att_d,
                                             hmat, (float*)d_out, N);
}